// Round 2
// baseline (304.537 us; speedup 1.0000x reference)
//
#include <hip/hip_runtime.h>

// DSSIM loss, B=32 C=3 H=W=512 fp32, 6x6 gaussian (sigma=1.5), VALID conv.
// R2: 2 output cols/thread, float2 loads, products computed once per element,
// t-loop unrolled x6 so the 6-deep vertical window rotates with compile-time
// indices (no register shifts). Inputs uniform [0,1) -> L=1 -> C1=1e-4, C2=9e-4.

#define HW           512
#define OUT_HW       507           // 512 - 6 + 1
#define PLANES       96            // B*C
#define ROWS_PER_BLK 64
#define NCHUNK       8             // ceil(507/64)

// unnormalized gaussian taps exp(-(x-3)^2/4.5), x=0..5 -> [g0,g1,g2,g3,g2,g1]
static constexpr double G0_ = 0.13533528323661270;  // exp(-2)
static constexpr double G1_ = 0.41111229050718745;  // exp(-8/9)
static constexpr double G2_ = 0.80073740291680810;  // exp(-2/9)
static constexpr double GS_ = G0_ + G1_ + G2_ + 1.0 + G2_ + G1_;

__device__ __constant__ const float GW[6] = {
    (float)(G0_ / GS_), (float)(G1_ / GS_), (float)(G2_ / GS_),
    (float)(1.0 / GS_), (float)(G2_ / GS_), (float)(G1_ / GS_)
};

__global__ __launch_bounds__(256, 3) void dssim_main(const float* __restrict__ x,
                                                     const float* __restrict__ y,
                                                     double* __restrict__ acc) {
    const float C1 = 1.0e-4f;
    const float C2 = 9.0e-4f;
    // local copy -> literal constants after unrolling
    const float gw[6] = {GW[0], GW[1], GW[2], GW[3], GW[4], GW[5]};

    const int tid = threadIdx.x;
    const int c0  = 2 * tid;            // output cols c0, c0+1
    const bool v0 = (c0     < OUT_HW);
    const bool v1 = (c0 + 1 < OUT_HW);

    const int row0  = blockIdx.x * ROWS_PER_BLK;
    const int plane = blockIdx.y;
    const int nrows = min(ROWS_PER_BLK, OUT_HW - row0);
    const int T     = nrows + 5;        // input rows touched (69 or 64)

    // clamped even element offsets (always in-image; garbage only feeds masked cols)
    const int e0 = c0;
    const int e1 = min(c0 + 2, 510);
    const int e2 = min(c0 + 4, 510);
    const int e3 = min(c0 + 6, 510);

    const size_t base = (size_t)plane * (HW * HW) + (size_t)row0 * HW;
    const float* px = x + base;
    const float* py = y + base;

    // 6-deep rotating windows of horizontally-filtered quantities, per column
    float hx0[6], hx1[6], hy0[6], hy1[6];
    float hxx0[6], hxx1[6], hyy0[6], hyy1[6], hxy0[6], hxy1[6];

    float sum = 0.0f;

    // ---- load row t, horizontal filter into window slot S (S compile-time) ----
#define ROW_BODY(TT, S)                                                         \
    {                                                                           \
        const float* xr = px + (size_t)(TT) * HW;                               \
        const float* yr = py + (size_t)(TT) * HW;                               \
        const float2 xa = *(const float2*)(xr + e0);                            \
        const float2 xb = *(const float2*)(xr + e1);                            \
        const float2 xc = *(const float2*)(xr + e2);                            \
        const float2 xd = *(const float2*)(xr + e3);                            \
        const float2 ya = *(const float2*)(yr + e0);                            \
        const float2 yb = *(const float2*)(yr + e1);                            \
        const float2 yc = *(const float2*)(yr + e2);                            \
        const float2 yd = *(const float2*)(yr + e3);                            \
        const float xv[8] = {xa.x, xa.y, xb.x, xb.y, xc.x, xc.y, xd.x, xd.y};   \
        const float yv[8] = {ya.x, ya.y, yb.x, yb.y, yc.x, yc.y, yd.x, yd.y};   \
        float pxx[7], pyy[7], pxy[7];                                           \
        _Pragma("unroll") for (int e = 0; e < 7; ++e) {                         \
            pxx[e] = xv[e] * xv[e];                                             \
            pyy[e] = yv[e] * yv[e];                                             \
            pxy[e] = xv[e] * yv[e];                                             \
        }                                                                       \
        float sx0 = 0.f, sy0 = 0.f, sxx0 = 0.f, syy0 = 0.f, sxy0 = 0.f;        \
        float sx1 = 0.f, sy1 = 0.f, sxx1 = 0.f, syy1 = 0.f, sxy1 = 0.f;        \
        _Pragma("unroll") for (int j = 0; j < 6; ++j) {                         \
            const float g = gw[j];                                              \
            sx0  += g * xv[j];      sx1  += g * xv[j + 1];                      \
            sy0  += g * yv[j];      sy1  += g * yv[j + 1];                      \
            sxx0 += g * pxx[j];     sxx1 += g * pxx[j + 1];                     \
            syy0 += g * pyy[j];     syy1 += g * pyy[j + 1];                     \
            sxy0 += g * pxy[j];     sxy1 += g * pxy[j + 1];                     \
        }                                                                       \
        hx0[S] = sx0;   hx1[S] = sx1;   hy0[S] = sy0;   hy1[S] = sy1;           \
        hxx0[S] = sxx0; hxx1[S] = sxx1; hyy0[S] = syy0; hyy1[S] = syy1;         \
        hxy0[S] = sxy0; hxy1[S] = sxy1;                                         \
    }

    // ---- vertical filter + SSIM for output row whose newest slot is S ----
#define OUT_BODY(S)                                                             \
    {                                                                           \
        float m10 = 0.f, m20 = 0.f, ex0 = 0.f, ey0 = 0.f, exy0 = 0.f;           \
        float m11 = 0.f, m21 = 0.f, ex1 = 0.f, ey1 = 0.f, exy1 = 0.f;           \
        _Pragma("unroll") for (int d = 0; d < 6; ++d) {                         \
            const int s = ((S) + 1 + d) % 6;                                    \
            const float g = gw[d];                                              \
            m10  += g * hx0[s];   m11  += g * hx1[s];                           \
            m20  += g * hy0[s];   m21  += g * hy1[s];                           \
            ex0  += g * hxx0[s];  ex1  += g * hxx1[s];                          \
            ey0  += g * hyy0[s];  ey1  += g * hyy1[s];                          \
            exy0 += g * hxy0[s];  exy1 += g * hxy1[s];                          \
        }                                                                       \
        {                                                                       \
            const float m1sq = m10 * m10, m2sq = m20 * m20, m12 = m10 * m20;    \
            const float s1 = ex0 - m1sq, s2 = ey0 - m2sq, s12 = exy0 - m12;     \
            const float vv1 = 2.0f * s12 + C2;                                  \
            const float vv2 = s1 + s2 + C2;                                     \
            const float num = (2.0f * m12 + C1) * vv1;                          \
            const float den = (m1sq + m2sq + C1) * vv2;                         \
            const float r   = num * __builtin_amdgcn_rcpf(den);                 \
            sum += v0 ? r : 0.0f;                                               \
        }                                                                       \
        {                                                                       \
            const float m1sq = m11 * m11, m2sq = m21 * m21, m12 = m11 * m21;    \
            const float s1 = ex1 - m1sq, s2 = ey1 - m2sq, s12 = exy1 - m12;     \
            const float vv1 = 2.0f * s12 + C2;                                  \
            const float vv2 = s1 + s2 + C2;                                     \
            const float num = (2.0f * m12 + C1) * vv1;                          \
            const float den = (m1sq + m2sq + C1) * vv2;                         \
            const float r   = num * __builtin_amdgcn_rcpf(den);                 \
            sum += v1 ? r : 0.0f;                                               \
        }                                                                       \
    }

    // prologue: rows 0..5 fill slots 0..5; row 5 emits first output row
    ROW_BODY(0, 0)
    ROW_BODY(1, 1)
    ROW_BODY(2, 2)
    ROW_BODY(3, 3)
    ROW_BODY(4, 4)
    ROW_BODY(5, 5)
    OUT_BODY(5)

    // main loop: groups of 6 rows, slot == phase (t6 multiple of 6)
    for (int t6 = 6; t6 < T; t6 += 6) {
#pragma unroll
        for (int p = 0; p < 6; ++p) {
            const int t = t6 + p;
            if (t < T) {
                switch (p) {   // compile-time slot per phase
                    case 0: ROW_BODY(t, 0) OUT_BODY(0) break;
                    case 1: ROW_BODY(t, 1) OUT_BODY(1) break;
                    case 2: ROW_BODY(t, 2) OUT_BODY(2) break;
                    case 3: ROW_BODY(t, 3) OUT_BODY(3) break;
                    case 4: ROW_BODY(t, 4) OUT_BODY(4) break;
                    case 5: ROW_BODY(t, 5) OUT_BODY(5) break;
                }
            }
        }
    }

#undef ROW_BODY
#undef OUT_BODY

    // ---- reduction: wave shfl -> LDS across 4 waves -> one f64 atomic per block
#pragma unroll
    for (int off = 32; off > 0; off >>= 1)
        sum += __shfl_down(sum, off, 64);

    __shared__ float wsum[4];
    const int wave = tid >> 6;
    const int lane = tid & 63;
    if (lane == 0) wsum[wave] = sum;
    __syncthreads();
    if (tid == 0) {
        double b = (double)wsum[0] + (double)wsum[1] + (double)wsum[2] + (double)wsum[3];
        atomicAdd(acc, b);
    }
}

__global__ void dssim_final(const double* __restrict__ acc, float* __restrict__ out) {
    const double n    = (double)PLANES * (double)OUT_HW * (double)OUT_HW;
    const double mean = acc[0] / n;
    out[0] = (float)((1.0 - mean) * 0.5);
}

extern "C" void kernel_launch(void* const* d_in, const int* in_sizes, int n_in,
                              void* d_out, int out_size, void* d_ws, size_t ws_size,
                              hipStream_t stream) {
    const float* x = (const float*)d_in[0];
    const float* y = (const float*)d_in[1];
    float* out  = (float*)d_out;
    double* acc = (double*)d_ws;

    hipMemsetAsync(acc, 0, sizeof(double), stream);

    dim3 grid(NCHUNK, PLANES);   // 8 x 96 = 768 blocks = 3 blocks/CU exactly
    dssim_main<<<grid, 256, 0, stream>>>(x, y, acc);
    dssim_final<<<1, 1, 0, stream>>>(acc, out);
}